// Round 1
// baseline (918.273 us; speedup 1.0000x reference)
//
#include <hip/hip_runtime.h>
#include <stdint.h>

#define NTOK 64
#define CDIM 384
#define NH   12
#define HD   32
#define SCALE 0.17677669529663687f  // 32^-0.5

typedef __attribute__((ext_vector_type(8))) short short8;
typedef __attribute__((ext_vector_type(4))) float floatx4;

__device__ __forceinline__ unsigned short f2bf(float f) {
    union { float f; unsigned u; } v; v.f = f;
    unsigned r = (v.u + 0x7fffu + ((v.u >> 16) & 1u)) >> 16;  // RNE
    return (unsigned short)r;
}

// ---------- prep: transpose weights to bf16 (W^T rows = output cols, contiguous K) ----------
__global__ void prep_weights(const float* __restrict__ qkv_w,
                             const float* __restrict__ proj_w,
                             unsigned short* __restrict__ qkv_wt,
                             unsigned short* __restrict__ proj_wt) {
    int i = blockIdx.x * blockDim.x + threadIdx.x;
    const int nq = 1152 * 384;
    const int np = 384 * 384;
    if (i < nq) {
        int r = i / 384, c = i - r * 384;          // qkv_wt[r][c] = qkv_w[c][r]
        qkv_wt[i] = f2bf(qkv_w[c * 1152 + r]);
    } else if (i < nq + np) {
        int o = i - nq;
        int r = o / 384, c = o - r * 384;
        proj_wt[o] = f2bf(proj_w[c * 384 + r]);
    }
}

// ---------- prep: relative-position bias table bt[h][i][j], 12x64x64 fp32 ----------
__global__ void prep_bias(const float* __restrict__ w1, const float* __restrict__ b1,
                          const float* __restrict__ w2, const float* __restrict__ b2,
                          float* __restrict__ bt) {
    int t = blockIdx.x * blockDim.x + threadIdx.x;  // 4096 threads
    int i = t >> 6, j = t & 63;
    float r0 = (float)((i >> 4) - (j >> 4));
    float r1 = (float)(((i >> 2) & 3) - ((j >> 2) & 3));
    float r2 = (float)((i & 3) - (j & 3));
    float acc[NH];
#pragma unroll
    for (int h = 0; h < NH; ++h) acc[h] = b2[h];
    for (int u = 0; u < 64; ++u) {
        float hv = r0 * w1[u] + r1 * w1[64 + u] + r2 * w1[128 + u] + b1[u];
        hv = fmaxf(hv, 0.f);
#pragma unroll
        for (int h = 0; h < NH; ++h) acc[h] += hv * w2[u * NH + h];
    }
    for (int h = 0; h < NH; ++h) bt[(h << 12) + (i << 6) + j] = acc[h];
}

// ---------- fused window attention: one block = one window, 512 threads / 8 waves ----------
#define XP  392   // xs/ao row stride (384+8): stride%32dw breaks LDS bank alias
#define QKP 40    // q/k row stride (32+8)
#define VTP 72    // vT row stride (64+8)
#define PBP 72    // P row stride (64+8)

__launch_bounds__(512, 2)
__global__ void win_attn(const float* __restrict__ x,
                         const unsigned short* __restrict__ qkv_wt,
                         const float* __restrict__ qkv_b,
                         const unsigned short* __restrict__ proj_wt,
                         const float* __restrict__ proj_b,
                         const float* __restrict__ bt,
                         float* __restrict__ out) {
    __shared__ unsigned short xs[64 * XP];          // x window, bf16       50176 B
    __shared__ unsigned short ao[64 * XP];          // attn out, bf16       50176 B
    __shared__ unsigned short qls[2][64 * QKP];     // q per head-pair      10240 B
    __shared__ unsigned short kls[2][64 * QKP];     // k per head-pair      10240 B
    __shared__ unsigned short vts[2][32 * VTP];     // v^T per head-pair     9216 B
    __shared__ unsigned short pbs[2][64 * PBP];     // P per head-pair      18432 B
                                                    // total 148480 B -> 1 block/CU, 8 waves
    const int tid  = threadIdx.x;
    const int lane = tid & 63;
    const int w    = tid >> 6;     // wave 0..7
    const int l15  = lane & 15;
    const int quad = lane >> 4;
    const int b    = blockIdx.x;

    // ---- stage x -> bf16 LDS (coalesced float4) ----
    const float* xb = x + (size_t)b * (64 * 384);
#pragma unroll
    for (int it = 0; it < 12; ++it) {
        int idx = it * 512 + tid;
        int row = idx / 96;                          // 96 float4 per row
        int c4  = idx - row * 96;
        const float4 v = *reinterpret_cast<const float4*>(xb + row * 384 + c4 * 4);
        uint2 pk;
        pk.x = (unsigned)f2bf(v.x) | ((unsigned)f2bf(v.y) << 16);
        pk.y = (unsigned)f2bf(v.z) | ((unsigned)f2bf(v.w) << 16);
        *reinterpret_cast<uint2*>(&xs[row * XP + c4 * 4]) = pk;
    }
    __syncthreads();

    // B1 role: 8 tasks = (head-in-pair, d-half, M-half)
    const int hh = w & 1;          // which head of the pair
    const int d2 = (w >> 1) & 1;   // which 16-wide d-half
    const int mh = w >> 2;         // which M-half (m-tiles 2mh, 2mh+1)
    // B2/B3 role: 8 tasks = (head-in-pair, 16-row block)
    const int hi = w >> 2;
    const int rb = w & 3;

    float rs[4];                   // 1/rowsum carried from softmax to PV epilogue
    const floatx4 zf4 = {0.f, 0.f, 0.f, 0.f};

#pragma unroll 1
    for (int hp = 0; hp < 6; ++hp) {
        // ======== B1: QKV GEMM for heads 2hp, 2hp+1 ========
        // wave w computes q,k,v (j=0,1,2) for head hh, d-half d2, m-tiles {2mh,2mh+1}
        floatx4 acc[3][2];
#pragma unroll
        for (int j = 0; j < 3; ++j)
#pragma unroll
            for (int mi = 0; mi < 2; ++mi) acc[j][mi] = zf4;

        int colbase[3];
#pragma unroll
        for (int j = 0; j < 3; ++j)
            colbase[j] = j * 384 + (2 * hp + hh) * 32 + d2 * 16;

#pragma unroll
        for (int kk = 0; kk < 12; ++kk) {
            short8 a[2];
#pragma unroll
            for (int mi = 0; mi < 2; ++mi)
                a[mi] = *reinterpret_cast<const short8*>(
                    &xs[(16 * (2 * mh + mi) + l15) * XP + kk * 32 + quad * 8]);
#pragma unroll
            for (int j = 0; j < 3; ++j) {
                const short8 bf = *reinterpret_cast<const short8*>(
                    qkv_wt + (size_t)(colbase[j] + l15) * 384 + kk * 32 + quad * 8);
#pragma unroll
                for (int mi = 0; mi < 2; ++mi)
                    acc[j][mi] = __builtin_amdgcn_mfma_f32_16x16x32_bf16(a[mi], bf, acc[j][mi], 0, 0, 0);
            }
        }
        // epilogue: +bias, q/k row-major, v transposed (packed 8B stores)
#pragma unroll
        for (int j = 0; j < 3; ++j) {
            const float bc = qkv_b[colbase[j] + l15];
            if (j < 2) {
                unsigned short* dst = (j == 0) ? qls[hh] : kls[hh];
#pragma unroll
                for (int mi = 0; mi < 2; ++mi)
#pragma unroll
                    for (int r = 0; r < 4; ++r) {
                        int tok = 16 * (2 * mh + mi) + quad * 4 + r;
                        dst[tok * QKP + d2 * 16 + l15] = f2bf(acc[j][mi][r] + bc);
                    }
            } else {
#pragma unroll
                for (int mi = 0; mi < 2; ++mi) {
                    uint2 pk;
                    pk.x = (unsigned)f2bf(acc[2][mi][0] + bc) | ((unsigned)f2bf(acc[2][mi][1] + bc) << 16);
                    pk.y = (unsigned)f2bf(acc[2][mi][2] + bc) | ((unsigned)f2bf(acc[2][mi][3] + bc) << 16);
                    *reinterpret_cast<uint2*>(
                        &vts[hh][(d2 * 16 + l15) * VTP + 16 * (2 * mh + mi) + quad * 4]) = pk;
                }
            }
        }
        __syncthreads();

        // ======== B2: S = qk^T*scale + bias, online row softmax ========
        // wave w owns rows 16rb..16rb+15 of head hi (one task per wave)
        {
            const int h = 2 * hp + hi;
            const short8 aq = *reinterpret_cast<const short8*>(
                &qls[hi][(16 * rb + l15) * QKP + quad * 8]);
            floatx4 s4[4];
#pragma unroll
            for (int c = 0; c < 4; ++c) {
                const short8 bk = *reinterpret_cast<const short8*>(
                    &kls[hi][(16 * c + l15) * QKP + quad * 8]);
                s4[c] = __builtin_amdgcn_mfma_f32_16x16x32_bf16(aq, bk, zf4, 0, 0, 0);
            }
            const float* bth = bt + ((size_t)h << 12);
#pragma unroll
            for (int r = 0; r < 4; ++r) {
                const int n = 16 * rb + quad * 4 + r;   // C-layout row
#pragma unroll
                for (int c = 0; c < 4; ++c)
                    s4[c][r] = s4[c][r] * SCALE + bth[(n << 6) + 16 * c + l15];
                float m0 = fmaxf(fmaxf(s4[0][r], s4[1][r]), fmaxf(s4[2][r], s4[3][r]));
#pragma unroll
                for (int sh = 1; sh < 16; sh <<= 1) m0 = fmaxf(m0, __shfl_xor(m0, sh, 16));
                float p0 = 0.f;
#pragma unroll
                for (int c = 0; c < 4; ++c) {
                    float p = __expf(s4[c][r] - m0);
                    s4[c][r] = p;
                    p0 += p;
                }
#pragma unroll
                for (int sh = 1; sh < 16; sh <<= 1) p0 += __shfl_xor(p0, sh, 16);
                rs[r] = 1.f / p0;
#pragma unroll
                for (int c = 0; c < 4; ++c)           // unnormalized P (<=1), bf16
                    pbs[hi][n * PBP + 16 * c + l15] = f2bf(s4[c][r]);
            }
        }

        // ======== B3: O = P @ V, normalize, assemble into ao ========
        // no barrier needed: pbs rows are same-wave produced/consumed; vts synced at B1 barrier
        {
            const int h = 2 * hp + hi;
            short8 ap[2];
#pragma unroll
            for (int kk = 0; kk < 2; ++kk)
                ap[kk] = *reinterpret_cast<const short8*>(
                    &pbs[hi][(16 * rb + l15) * PBP + kk * 32 + quad * 8]);
#pragma unroll
            for (int t = 0; t < 2; ++t) {
                floatx4 oacc = zf4;
#pragma unroll
                for (int kk = 0; kk < 2; ++kk) {
                    const short8 bv = *reinterpret_cast<const short8*>(
                        &vts[hi][(16 * t + l15) * VTP + kk * 32 + quad * 8]);
                    oacc = __builtin_amdgcn_mfma_f32_16x16x32_bf16(ap[kk], bv, oacc, 0, 0, 0);
                }
#pragma unroll
                for (int r = 0; r < 4; ++r) {
                    int tok = 16 * rb + quad * 4 + r;
                    ao[tok * XP + h * 32 + 16 * t + l15] = f2bf(oacc[r] * rs[r]);
                }
            }
        }
        __syncthreads();
    }

    // ======== proj: out = ao(64x384) @ proj_w + proj_b ========
    // 24 N-tiles over 8 waves, single pass, 3 tiles each
    float* ob = out + (size_t)b * (64 * 384);
    {
        const int ntb = w * 3;
        floatx4 acc2[3][4];
#pragma unroll
        for (int j = 0; j < 3; ++j)
#pragma unroll
            for (int m = 0; m < 4; ++m) acc2[j][m] = zf4;

#pragma unroll
        for (int kk = 0; kk < 12; ++kk) {
            short8 a2[4];
#pragma unroll
            for (int m = 0; m < 4; ++m)
                a2[m] = *reinterpret_cast<const short8*>(
                    &ao[(16 * m + l15) * XP + kk * 32 + quad * 8]);
#pragma unroll
            for (int j = 0; j < 3; ++j) {
                const short8 bf = *reinterpret_cast<const short8*>(
                    proj_wt + (size_t)((ntb + j) * 16 + l15) * 384 + kk * 32 + quad * 8);
#pragma unroll
                for (int m = 0; m < 4; ++m)
                    acc2[j][m] = __builtin_amdgcn_mfma_f32_16x16x32_bf16(a2[m], bf, acc2[j][m], 0, 0, 0);
            }
        }
#pragma unroll
        for (int j = 0; j < 3; ++j) {
            const int col = (ntb + j) * 16 + l15;
            const float pbias = proj_b[col];
#pragma unroll
            for (int m = 0; m < 4; ++m)
#pragma unroll
                for (int r = 0; r < 4; ++r)
                    ob[(16 * m + quad * 4 + r) * 384 + col] = acc2[j][m][r] + pbias;
        }
    }
}

extern "C" void kernel_launch(void* const* d_in, const int* in_sizes, int n_in,
                              void* d_out, int out_size, void* d_ws, size_t ws_size,
                              hipStream_t stream) {
    const float* x      = (const float*)d_in[0];
    const float* qkv_w  = (const float*)d_in[1];
    const float* qkv_b  = (const float*)d_in[2];
    const float* proj_w = (const float*)d_in[3];
    const float* proj_b = (const float*)d_in[4];
    const float* mlp_w1 = (const float*)d_in[5];
    const float* mlp_b1 = (const float*)d_in[6];
    const float* mlp_w2 = (const float*)d_in[7];
    const float* mlp_b2 = (const float*)d_in[8];
    float* out = (float*)d_out;

    // workspace layout (re-written every launch; harness poisons ws)
    unsigned short* qkv_wt  = (unsigned short*)d_ws;              // 1152*384 bf16
    unsigned short* proj_wt = qkv_wt + 1152 * 384;                // 384*384 bf16
    float*          bt      = (float*)(proj_wt + 384 * 384);      // 12*64*64 fp32

    prep_weights<<<2304, 256, 0, stream>>>(qkv_w, proj_w, qkv_wt, proj_wt);
    prep_bias<<<16, 256, 0, stream>>>(mlp_w1, mlp_b1, mlp_w2, mlp_b2, bt);
    win_attn<<<2048, 512, 0, stream>>>(x, qkv_wt, qkv_b, proj_wt, proj_b, bt, out);
}

// Round 2
// 844.525 us; speedup vs baseline: 1.0873x; 1.0873x over previous
//
#include <hip/hip_runtime.h>
#include <stdint.h>

#define SCALE 0.17677669529663687f  // 32^-0.5

typedef __attribute__((ext_vector_type(8))) short short8;
typedef __attribute__((ext_vector_type(4))) float floatx4;

__device__ __forceinline__ unsigned short f2bf(float f) {
    union { float f; unsigned u; } v; v.f = f;
    unsigned r = (v.u + 0x7fffu + ((v.u >> 16) & 1u)) >> 16;  // RNE
    return (unsigned short)r;
}

// ---------- prep: transpose weights to bf16 (W^T rows = output cols, contiguous K) ----------
__global__ void prep_weights(const float* __restrict__ qkv_w,
                             const float* __restrict__ proj_w,
                             unsigned short* __restrict__ qkv_wt,
                             unsigned short* __restrict__ proj_wt) {
    int i = blockIdx.x * blockDim.x + threadIdx.x;
    const int nq = 1152 * 384;
    const int np = 384 * 384;
    if (i < nq) {
        int r = i / 384, c = i - r * 384;          // qkv_wt[r][c] = qkv_w[c][r]
        qkv_wt[i] = f2bf(qkv_w[c * 1152 + r]);
    } else if (i < nq + np) {
        int o = i - nq;
        int r = o / 384, c = o - r * 384;
        proj_wt[o] = f2bf(proj_w[c * 384 + r]);
    }
}

// ---------- prep: relative-position bias table bt[h][i][j], 12x64x64 fp32 ----------
__global__ void prep_bias(const float* __restrict__ w1, const float* __restrict__ b1,
                          const float* __restrict__ w2, const float* __restrict__ b2,
                          float* __restrict__ bt) {
    int t = blockIdx.x * blockDim.x + threadIdx.x;  // 4096 threads
    int i = t >> 6, j = t & 63;
    float r0 = (float)((i >> 4) - (j >> 4));
    float r1 = (float)(((i >> 2) & 3) - ((j >> 2) & 3));
    float r2 = (float)((i & 3) - (j & 3));
    float acc[12];
#pragma unroll
    for (int h = 0; h < 12; ++h) acc[h] = b2[h];
    for (int u = 0; u < 64; ++u) {
        float hv = r0 * w1[u] + r1 * w1[64 + u] + r2 * w1[128 + u] + b1[u];
        hv = fmaxf(hv, 0.f);
#pragma unroll
        for (int h = 0; h < 12; ++h) acc[h] += hv * w2[u * 12 + h];
    }
    for (int h = 0; h < 12; ++h) bt[(h << 12) + (i << 6) + j] = acc[h];
}

// ---------- fused window attention: one block = one window, 384 threads / 6 waves ----------
// One head per iteration; proj accumulated in registers (no ao buffer, no proj phase).
// LDS 79360 B -> 2 independent blocks/CU (the latency-hiding lever this round).
#define XP  392   // xs row stride (384+8)
#define QKP 40    // q/k row stride (32+8)
#define VTP 72    // vT row stride (64+8)
#define PBP 72    // P row stride (64+8)
#define OSP 40    // O-slice row stride (32+8)

__launch_bounds__(384, 3)
__global__ void win_attn(const float* __restrict__ x,
                         const unsigned short* __restrict__ qkv_wt,
                         const float* __restrict__ qkv_b,
                         const unsigned short* __restrict__ proj_wt,
                         const float* __restrict__ proj_b,
                         const float* __restrict__ bt,
                         float* __restrict__ out) {
    __shared__ unsigned short xs[64 * XP];     // x window, bf16      50176 B
    __shared__ unsigned short ql[64 * QKP];    // q (current head)     5120 B
    __shared__ unsigned short kl[64 * QKP];    // k (current head)     5120 B
    __shared__ unsigned short vt[32 * VTP];    // v^T (current head)   4608 B
    __shared__ unsigned short pb[64 * PBP];    // P (current head)     9216 B
    __shared__ unsigned short osl[64 * OSP];   // O-slice 64x32        5120 B
                                               // total 79360 B -> 2 blocks/CU
    const int tid  = threadIdx.x;
    const int lane = tid & 63;
    const int w    = tid >> 6;     // wave 0..5
    const int l15  = lane & 15;
    const int quad = lane >> 4;
    const int b    = blockIdx.x;

    // ---- stage x -> bf16 LDS (coalesced float4) ----
    const float* xb = x + (size_t)b * (64 * 384);
#pragma unroll
    for (int it = 0; it < 16; ++it) {
        int idx = it * 384 + tid;
        int row = idx / 96;                          // 96 float4 per row
        int c4  = idx - row * 96;
        const float4 v = *reinterpret_cast<const float4*>(xb + row * 384 + c4 * 4);
        uint2 pk;
        pk.x = (unsigned)f2bf(v.x) | ((unsigned)f2bf(v.y) << 16);
        pk.y = (unsigned)f2bf(v.z) | ((unsigned)f2bf(v.w) << 16);
        *reinterpret_cast<uint2*>(&xs[row * XP + c4 * 4]) = pk;
    }
    __syncthreads();

    // B1 role: wave w owns one 16-wide N-tile of [q0 q1 k0 k1 v0 v1]
    const int j3 = w >> 1;         // 0=q, 1=k, 2=v
    const int d2 = w & 1;          // which 16-wide d-half
    const floatx4 zf4 = {0.f, 0.f, 0.f, 0.f};

    floatx4 acc2[4][4];            // persistent proj accumulator: 4 N-tiles x 4 M-tiles
#pragma unroll
    for (int jj = 0; jj < 4; ++jj)
#pragma unroll
        for (int m = 0; m < 4; ++m) acc2[jj][m] = zf4;

    float rs[4];                   // 1/rowsum (waves 0..3 only)

#pragma unroll 1
    for (int h = 0; h < 12; ++h) {
        // ======== B1: q,k,v for head h; wave = one 16-col output tile, all 4 M-tiles ========
        floatx4 acc[4];
#pragma unroll
        for (int m = 0; m < 4; ++m) acc[m] = zf4;
        const int colbase = j3 * 384 + h * 32 + d2 * 16;
        const unsigned short* wcol = qkv_wt + (size_t)(colbase + l15) * 384;

#pragma unroll
        for (int kk = 0; kk < 12; ++kk) {
            const short8 bf = *reinterpret_cast<const short8*>(wcol + kk * 32 + quad * 8);
            short8 a[4];
#pragma unroll
            for (int m = 0; m < 4; ++m)
                a[m] = *reinterpret_cast<const short8*>(
                    &xs[(16 * m + l15) * XP + kk * 32 + quad * 8]);
#pragma unroll
            for (int m = 0; m < 4; ++m)
                acc[m] = __builtin_amdgcn_mfma_f32_16x16x32_bf16(a[m], bf, acc[m], 0, 0, 0);
        }
        // epilogue: +bias; q/k row-major, v transposed (packed 8B stores)
        {
            const float bc = qkv_b[colbase + l15];
            if (j3 < 2) {
                unsigned short* dst = (j3 == 0) ? ql : kl;
#pragma unroll
                for (int m = 0; m < 4; ++m)
#pragma unroll
                    for (int r = 0; r < 4; ++r)
                        dst[(16 * m + quad * 4 + r) * QKP + d2 * 16 + l15] = f2bf(acc[m][r] + bc);
            } else {
#pragma unroll
                for (int m = 0; m < 4; ++m) {
                    uint2 pk;
                    pk.x = (unsigned)f2bf(acc[m][0] + bc) | ((unsigned)f2bf(acc[m][1] + bc) << 16);
                    pk.y = (unsigned)f2bf(acc[m][2] + bc) | ((unsigned)f2bf(acc[m][3] + bc) << 16);
                    *reinterpret_cast<uint2*>(
                        &vt[(d2 * 16 + l15) * VTP + 16 * m + quad * 4]) = pk;
                }
            }
        }
        __syncthreads();

        // ======== B2: S = q k^T * scale + bias, row softmax; B3: O = P @ V ========
        // waves 0..3 own 16-row blocks; pb/osl rows produced+consumed same-wave (no barrier between)
        if (w < 4) {
            const short8 aq = *reinterpret_cast<const short8*>(
                &ql[(16 * w + l15) * QKP + quad * 8]);
            floatx4 s4[4];
#pragma unroll
            for (int c = 0; c < 4; ++c) {
                const short8 bk = *reinterpret_cast<const short8*>(
                    &kl[(16 * c + l15) * QKP + quad * 8]);
                s4[c] = __builtin_amdgcn_mfma_f32_16x16x32_bf16(aq, bk, zf4, 0, 0, 0);
            }
            const float* bth = bt + ((size_t)h << 12);
#pragma unroll
            for (int r = 0; r < 4; ++r) {
                const int n = 16 * w + quad * 4 + r;   // C-layout row
#pragma unroll
                for (int c = 0; c < 4; ++c)
                    s4[c][r] = s4[c][r] * SCALE + bth[(n << 6) + 16 * c + l15];
                float m0 = fmaxf(fmaxf(s4[0][r], s4[1][r]), fmaxf(s4[2][r], s4[3][r]));
#pragma unroll
                for (int sh = 1; sh < 16; sh <<= 1) m0 = fmaxf(m0, __shfl_xor(m0, sh, 16));
                float p0 = 0.f;
#pragma unroll
                for (int c = 0; c < 4; ++c) {
                    float p = __expf(s4[c][r] - m0);
                    s4[c][r] = p;
                    p0 += p;
                }
#pragma unroll
                for (int sh = 1; sh < 16; sh <<= 1) p0 += __shfl_xor(p0, sh, 16);
                rs[r] = 1.f / p0;
#pragma unroll
                for (int c = 0; c < 4; ++c)           // unnormalized P (<=1), bf16
                    pb[n * PBP + 16 * c + l15] = f2bf(s4[c][r]);
            }
            // B3
            short8 ap[2];
#pragma unroll
            for (int kkp = 0; kkp < 2; ++kkp)
                ap[kkp] = *reinterpret_cast<const short8*>(
                    &pb[(16 * w + l15) * PBP + kkp * 32 + quad * 8]);
#pragma unroll
            for (int t = 0; t < 2; ++t) {
                floatx4 oacc = zf4;
#pragma unroll
                for (int kkp = 0; kkp < 2; ++kkp) {
                    const short8 bv = *reinterpret_cast<const short8*>(
                        &vt[(16 * t + l15) * VTP + kkp * 32 + quad * 8]);
                    oacc = __builtin_amdgcn_mfma_f32_16x16x32_bf16(ap[kkp], bv, oacc, 0, 0, 0);
                }
#pragma unroll
                for (int r = 0; r < 4; ++r)
                    osl[(16 * w + quad * 4 + r) * OSP + 16 * t + l15] = f2bf(oacc[r] * rs[r]);
            }
        }
        __syncthreads();

        // ======== proj accumulate: out += O_h @ proj_wt[:, h*32 .. h*32+32] ========
        // wave w owns N-tiles 4w..4w+3; K=32 slice per head -> 1 MFMA per (nt, mt)
        {
            short8 a2[4];
#pragma unroll
            for (int m = 0; m < 4; ++m)
                a2[m] = *reinterpret_cast<const short8*>(
                    &osl[(16 * m + l15) * OSP + quad * 8]);
#pragma unroll
            for (int jj = 0; jj < 4; ++jj) {
                const short8 b2 = *reinterpret_cast<const short8*>(
                    proj_wt + (size_t)((w * 4 + jj) * 16 + l15) * 384 + h * 32 + quad * 8);
#pragma unroll
                for (int m = 0; m < 4; ++m)
                    acc2[jj][m] = __builtin_amdgcn_mfma_f32_16x16x32_bf16(a2[m], b2, acc2[jj][m], 0, 0, 0);
            }
        }
        // no barrier here: next B1 writes ql/kl/vt (read only before barrier-2);
        // next B3 writes osl only after the next post-B1 barrier.
    }

    // ======== epilogue: out = acc2 + proj_b ========
    float* ob = out + (size_t)b * (64 * 384);
#pragma unroll
    for (int jj = 0; jj < 4; ++jj) {
        const int col = (w * 4 + jj) * 16 + l15;
        const float pbias = proj_b[col];
#pragma unroll
        for (int m = 0; m < 4; ++m)
#pragma unroll
            for (int r = 0; r < 4; ++r)
                ob[(16 * m + quad * 4 + r) * 384 + col] = acc2[jj][m][r] + pbias;
    }
}

extern "C" void kernel_launch(void* const* d_in, const int* in_sizes, int n_in,
                              void* d_out, int out_size, void* d_ws, size_t ws_size,
                              hipStream_t stream) {
    const float* x      = (const float*)d_in[0];
    const float* qkv_w  = (const float*)d_in[1];
    const float* qkv_b  = (const float*)d_in[2];
    const float* proj_w = (const float*)d_in[3];
    const float* proj_b = (const float*)d_in[4];
    const float* mlp_w1 = (const float*)d_in[5];
    const float* mlp_b1 = (const float*)d_in[6];
    const float* mlp_w2 = (const float*)d_in[7];
    const float* mlp_b2 = (const float*)d_in[8];
    float* out = (float*)d_out;

    // workspace layout (re-written every launch; harness poisons ws)
    unsigned short* qkv_wt  = (unsigned short*)d_ws;              // 1152*384 bf16
    unsigned short* proj_wt = qkv_wt + 1152 * 384;                // 384*384 bf16
    float*          bt      = (float*)(proj_wt + 384 * 384);      // 12*64*64 fp32

    prep_weights<<<2304, 256, 0, stream>>>(qkv_w, proj_w, qkv_wt, proj_wt);
    prep_bias<<<16, 256, 0, stream>>>(mlp_w1, mlp_b1, mlp_w2, mlp_b2, bt);
    win_attn<<<2048, 384, 0, stream>>>(x, qkv_wt, qkv_b, proj_wt, proj_b, bt, out);
}

// Round 3
// 782.971 us; speedup vs baseline: 1.1728x; 1.0786x over previous
//
#include <hip/hip_runtime.h>
#include <stdint.h>

#define SCALE 0.17677669529663687f  // 32^-0.5

typedef __attribute__((ext_vector_type(8))) short short8;
typedef __attribute__((ext_vector_type(4))) float floatx4;

__device__ __forceinline__ unsigned short f2bf(float f) {
    union { float f; unsigned u; } v; v.f = f;
    unsigned r = (v.u + 0x7fffu + ((v.u >> 16) & 1u)) >> 16;  // RNE
    return (unsigned short)r;
}

// ---------- prep: transpose weights to bf16 (W^T rows = output cols, contiguous K) ----------
__global__ void prep_weights(const float* __restrict__ qkv_w,
                             const float* __restrict__ proj_w,
                             unsigned short* __restrict__ qkv_wt,
                             unsigned short* __restrict__ proj_wt) {
    int i = blockIdx.x * blockDim.x + threadIdx.x;
    const int nq = 1152 * 384;
    const int np = 384 * 384;
    if (i < nq) {
        int r = i / 384, c = i - r * 384;          // qkv_wt[r][c] = qkv_w[c][r]
        qkv_wt[i] = f2bf(qkv_w[c * 1152 + r]);
    } else if (i < nq + np) {
        int o = i - nq;
        int r = o / 384, c = o - r * 384;
        proj_wt[o] = f2bf(proj_w[c * 384 + r]);
    }
}

// ---------- prep: relative-position bias table bt[h][i][j], 12x64x64 fp32 ----------
__global__ void prep_bias(const float* __restrict__ w1, const float* __restrict__ b1,
                          const float* __restrict__ w2, const float* __restrict__ b2,
                          float* __restrict__ bt) {
    int t = blockIdx.x * blockDim.x + threadIdx.x;  // 4096 threads
    int i = t >> 6, j = t & 63;
    float r0 = (float)((i >> 4) - (j >> 4));
    float r1 = (float)(((i >> 2) & 3) - ((j >> 2) & 3));
    float r2 = (float)((i & 3) - (j & 3));
    float acc[12];
#pragma unroll
    for (int h = 0; h < 12; ++h) acc[h] = b2[h];
    for (int u = 0; u < 64; ++u) {
        float hv = r0 * w1[u] + r1 * w1[64 + u] + r2 * w1[128 + u] + b1[u];
        hv = fmaxf(hv, 0.f);
#pragma unroll
        for (int h = 0; h < 12; ++h) acc[h] += hv * w2[u * 12 + h];
    }
    for (int h = 0; h < 12; ++h) bt[(h << 12) + (i << 6) + j] = acc[h];
}

// ---------- fused window attention: one block = one window, 384 threads / 6 waves ----------
// Head-PAIR pipeline: per pair p: [B1(p)] barrier [B23(p) || proj(p-1)] barrier.
// 13 barriers/block (vs 26), A-frag LDS traffic halved, proj deferred via double osl.
#define XP  392   // xs row stride (384+8 shorts)
#define QKP 40    // q/k row stride (32+8)
#define VTP 72    // vT row stride (64+8)
#define PBP 72    // P row stride (64+8)
#define OSP 72    // osl row stride (64+8): 64 cols = 2 heads x 32d

__launch_bounds__(384, 2)
__global__ void win_attn(const float* __restrict__ x,
                         const unsigned short* __restrict__ qkv_wt,
                         const float* __restrict__ qkv_b,
                         const unsigned short* __restrict__ proj_wt,
                         const float* __restrict__ proj_b,
                         const float* __restrict__ bt,
                         float* __restrict__ out) {
    __shared__ unsigned short xs[64 * XP];         // x window bf16          50176 B
    __shared__ unsigned short ql[2][64 * QKP];     // q, per head-in-pair    10240 B
    __shared__ unsigned short kl[2][64 * QKP];     // k                      10240 B
    __shared__ unsigned short vt[2][32 * VTP];     // v^T                     9216 B
    __shared__ unsigned short pb[2][4][16 * PBP];  // P [head][rowblock]     18432 B
    __shared__ unsigned short osl[2][64 * OSP];    // O pair-slice, dbuf     18432 B
                                                   // total 116736 B -> 1 block/CU
    const int tid  = threadIdx.x;
    const int lane = tid & 63;
    const int w    = tid >> 6;     // wave 0..5
    const int l15  = lane & 15;
    const int quad = lane >> 4;
    const int b    = blockIdx.x;

    // ---- stage x -> bf16 LDS (coalesced float4) ----
    const float* xb = x + (size_t)b * (64 * 384);
#pragma unroll
    for (int it = 0; it < 16; ++it) {
        int idx = it * 384 + tid;
        int row = idx / 96;                          // 96 float4 per row
        int c4  = idx - row * 96;
        const float4 v = *reinterpret_cast<const float4*>(xb + row * 384 + c4 * 4);
        uint2 pk;
        pk.x = (unsigned)f2bf(v.x) | ((unsigned)f2bf(v.y) << 16);
        pk.y = (unsigned)f2bf(v.z) | ((unsigned)f2bf(v.w) << 16);
        *reinterpret_cast<uint2*>(&xs[row * XP + c4 * 4]) = pk;
    }
    __syncthreads();

    // B1 role: wave w -> (q/k/v) = w>>1, d-half = w&1; both heads of the pair.
    const int j3 = w >> 1;
    const int d2 = w & 1;
    // proj role: waves 0-3 own 5 N-tiles, waves 4-5 own 2 (balances extra B23 on 4,5)
    const int ntile = (w < 4) ? 5 : 2;
    const int t0    = (w < 4) ? 5 * w : (20 + 2 * (w - 4));

    const floatx4 zf4 = {0.f, 0.f, 0.f, 0.f};
    floatx4 acc2[5][4];            // persistent proj accumulator
#pragma unroll
    for (int jj = 0; jj < 5; ++jj)
#pragma unroll
        for (int m = 0; m < 4; ++m) acc2[jj][m] = zf4;

#define PROJ_STEP(PP)                                                                   \
    {                                                                                   \
        const int buf_ = (PP) & 1;                                                      \
        short8 a2_[4][2];                                                               \
        _Pragma("unroll")                                                               \
        for (int m = 0; m < 4; ++m)                                                     \
            _Pragma("unroll")                                                           \
            for (int k2 = 0; k2 < 2; ++k2)                                              \
                a2_[m][k2] = *reinterpret_cast<const short8*>(                          \
                    &osl[buf_][(16 * m + l15) * OSP + k2 * 32 + quad * 8]);             \
        _Pragma("unroll")                                                               \
        for (int jj = 0; jj < 5; ++jj)                                                  \
            if (jj < ntile) {                                                           \
                const unsigned short* pw =                                              \
                    proj_wt + (size_t)((t0 + jj) * 16 + l15) * 384 + (PP) * 64;         \
                const short8 b20 = *reinterpret_cast<const short8*>(pw + quad * 8);     \
                const short8 b21 = *reinterpret_cast<const short8*>(pw + 32 + quad * 8);\
                _Pragma("unroll")                                                       \
                for (int m = 0; m < 4; ++m) {                                           \
                    acc2[jj][m] = __builtin_amdgcn_mfma_f32_16x16x32_bf16(              \
                        a2_[m][0], b20, acc2[jj][m], 0, 0, 0);                          \
                    acc2[jj][m] = __builtin_amdgcn_mfma_f32_16x16x32_bf16(              \
                        a2_[m][1], b21, acc2[jj][m], 0, 0, 0);                          \
                }                                                                       \
            }                                                                           \
    }

#pragma unroll 1
    for (int p = 0; p < 6; ++p) {
        // ======== phase A: B1(pair p) — q,k,v for heads 2p, 2p+1 ========
        floatx4 acc[2][4];
#pragma unroll
        for (int hh = 0; hh < 2; ++hh)
#pragma unroll
            for (int m = 0; m < 4; ++m) acc[hh][m] = zf4;

        int colbase[2];
#pragma unroll
        for (int hh = 0; hh < 2; ++hh)
            colbase[hh] = j3 * 384 + (2 * p + hh) * 32 + d2 * 16;
        const unsigned short* wcol0 = qkv_wt + (size_t)(colbase[0] + l15) * 384;
        const unsigned short* wcol1 = qkv_wt + (size_t)(colbase[1] + l15) * 384;

#pragma unroll
        for (int kk = 0; kk < 12; ++kk) {
            short8 a[4];
#pragma unroll
            for (int m = 0; m < 4; ++m)
                a[m] = *reinterpret_cast<const short8*>(
                    &xs[(16 * m + l15) * XP + kk * 32 + quad * 8]);
            const short8 bf0 = *reinterpret_cast<const short8*>(wcol0 + kk * 32 + quad * 8);
            const short8 bf1 = *reinterpret_cast<const short8*>(wcol1 + kk * 32 + quad * 8);
#pragma unroll
            for (int m = 0; m < 4; ++m) {
                acc[0][m] = __builtin_amdgcn_mfma_f32_16x16x32_bf16(a[m], bf0, acc[0][m], 0, 0, 0);
                acc[1][m] = __builtin_amdgcn_mfma_f32_16x16x32_bf16(a[m], bf1, acc[1][m], 0, 0, 0);
            }
        }
        // epilogue: +bias; q/k row-major, v transposed (packed 8B stores)
#pragma unroll
        for (int hh = 0; hh < 2; ++hh) {
            const float bc = qkv_b[colbase[hh] + l15];
            if (j3 < 2) {
                unsigned short* dst = (j3 == 0) ? ql[hh] : kl[hh];
#pragma unroll
                for (int m = 0; m < 4; ++m)
#pragma unroll
                    for (int r = 0; r < 4; ++r)
                        dst[(16 * m + quad * 4 + r) * QKP + d2 * 16 + l15] =
                            f2bf(acc[hh][m][r] + bc);
            } else {
#pragma unroll
                for (int m = 0; m < 4; ++m) {
                    uint2 pk;
                    pk.x = (unsigned)f2bf(acc[hh][m][0] + bc) | ((unsigned)f2bf(acc[hh][m][1] + bc) << 16);
                    pk.y = (unsigned)f2bf(acc[hh][m][2] + bc) | ((unsigned)f2bf(acc[hh][m][3] + bc) << 16);
                    *reinterpret_cast<uint2*>(
                        &vt[hh][(d2 * 16 + l15) * VTP + 16 * m + quad * 4]) = pk;
                }
            }
        }
        __syncthreads();

        // ======== phase B: B23(pair p) || proj(pair p-1) ========
        // B23 tasks (head-in-pair, rowblock): waves 0-3 -> (0, w); waves 4,5 -> (1, w-4) and (1, w-2)
        const int ntask = (w < 4) ? 1 : 2;
#pragma unroll 1
        for (int tk = 0; tk < ntask; ++tk) {
            const int h  = (w < 4) ? 0 : 1;
            const int rb = (w < 4) ? w : ((w - 4) + 2 * tk);
            const int hg = 2 * p + h;

            const short8 aq = *reinterpret_cast<const short8*>(
                &ql[h][(16 * rb + l15) * QKP + quad * 8]);
            floatx4 s4[4];
#pragma unroll
            for (int c = 0; c < 4; ++c) {
                const short8 bk = *reinterpret_cast<const short8*>(
                    &kl[h][(16 * c + l15) * QKP + quad * 8]);
                s4[c] = __builtin_amdgcn_mfma_f32_16x16x32_bf16(aq, bk, zf4, 0, 0, 0);
            }
            const float* bth = bt + ((size_t)hg << 12);
            float rs[4];
#pragma unroll
            for (int r = 0; r < 4; ++r) {
                const int n = 16 * rb + quad * 4 + r;   // C-layout row
#pragma unroll
                for (int c = 0; c < 4; ++c)
                    s4[c][r] = s4[c][r] * SCALE + bth[(n << 6) + 16 * c + l15];
                float m0 = fmaxf(fmaxf(s4[0][r], s4[1][r]), fmaxf(s4[2][r], s4[3][r]));
#pragma unroll
                for (int sh = 1; sh < 16; sh <<= 1) m0 = fmaxf(m0, __shfl_xor(m0, sh, 16));
                float p0 = 0.f;
#pragma unroll
                for (int c = 0; c < 4; ++c) {
                    float pv = __expf(s4[c][r] - m0);
                    s4[c][r] = pv;
                    p0 += pv;
                }
#pragma unroll
                for (int sh = 1; sh < 16; sh <<= 1) p0 += __shfl_xor(p0, sh, 16);
                rs[r] = 1.f / p0;
#pragma unroll
                for (int c = 0; c < 4; ++c)           // unnormalized P (<=1), bf16
                    pb[h][rb][(quad * 4 + r) * PBP + 16 * c + l15] = f2bf(s4[c][r]);
            }
            // B3: O = P @ V into osl[p&1], cols h*32..h*32+32
            short8 ap[2];
#pragma unroll
            for (int kkp = 0; kkp < 2; ++kkp)
                ap[kkp] = *reinterpret_cast<const short8*>(
                    &pb[h][rb][l15 * PBP + kkp * 32 + quad * 8]);
#pragma unroll
            for (int t = 0; t < 2; ++t) {
                floatx4 oacc = zf4;
#pragma unroll
                for (int kkp = 0; kkp < 2; ++kkp) {
                    const short8 bv = *reinterpret_cast<const short8*>(
                        &vt[h][(16 * t + l15) * VTP + kkp * 32 + quad * 8]);
                    oacc = __builtin_amdgcn_mfma_f32_16x16x32_bf16(ap[kkp], bv, oacc, 0, 0, 0);
                }
#pragma unroll
                for (int r = 0; r < 4; ++r)
                    osl[p & 1][(16 * rb + quad * 4 + r) * OSP + h * 32 + 16 * t + l15] =
                        f2bf(oacc[r] * rs[r]);
            }
        }
        // proj for previous pair (reads osl[(p-1)&1] — written last iteration, barrier-separated)
        if (p >= 1) PROJ_STEP(p - 1);
        __syncthreads();
    }
    // final pair's proj (osl[1] written in p=5 phase B, barrier passed)
    PROJ_STEP(5);

    // ======== epilogue: out = acc2 + proj_b ========
    float* ob = out + (size_t)b * (64 * 384);
#pragma unroll
    for (int jj = 0; jj < 5; ++jj)
        if (jj < ntile) {
            const int col = (t0 + jj) * 16 + l15;
            const float pbias = proj_b[col];
#pragma unroll
            for (int m = 0; m < 4; ++m)
#pragma unroll
                for (int r = 0; r < 4; ++r)
                    ob[(16 * m + quad * 4 + r) * 384 + col] = acc2[jj][m][r] + pbias;
        }
#undef PROJ_STEP
}

extern "C" void kernel_launch(void* const* d_in, const int* in_sizes, int n_in,
                              void* d_out, int out_size, void* d_ws, size_t ws_size,
                              hipStream_t stream) {
    const float* x      = (const float*)d_in[0];
    const float* qkv_w  = (const float*)d_in[1];
    const float* qkv_b  = (const float*)d_in[2];
    const float* proj_w = (const float*)d_in[3];
    const float* proj_b = (const float*)d_in[4];
    const float* mlp_w1 = (const float*)d_in[5];
    const float* mlp_b1 = (const float*)d_in[6];
    const float* mlp_w2 = (const float*)d_in[7];
    const float* mlp_b2 = (const float*)d_in[8];
    float* out = (float*)d_out;

    // workspace layout (re-written every launch; harness poisons ws)
    unsigned short* qkv_wt  = (unsigned short*)d_ws;              // 1152*384 bf16
    unsigned short* proj_wt = qkv_wt + 1152 * 384;                // 384*384 bf16
    float*          bt      = (float*)(proj_wt + 384 * 384);      // 12*64*64 fp32

    prep_weights<<<2304, 256, 0, stream>>>(qkv_w, proj_w, qkv_wt, proj_wt);
    prep_bias<<<16, 256, 0, stream>>>(mlp_w1, mlp_b1, mlp_w2, mlp_b2, bt);
    win_attn<<<2048, 384, 0, stream>>>(x, qkv_wt, qkv_b, proj_wt, proj_b, bt, out);
}